// Round 9
// baseline (164.919 us; speedup 1.0000x reference)
//
#include <hip/hip_runtime.h>
#include <hip/hip_bf16.h>

constexpr int BB = 4;
constexpr int TT = 1024;
constexpr int DD = 512;
constexpr int PP = 64;
constexpr int MM = 256;

constexpr float CSCALE = 2.8853900817779268f; // 2*log2(e)
constexpr float L2E = 1.4426950408889634f;    // log2(e)

typedef __attribute__((ext_vector_type(8))) short v8s;
typedef __attribute__((ext_vector_type(4))) float v4f;
typedef unsigned int __attribute__((address_space(1))) gu32;
typedef unsigned int __attribute__((address_space(3))) su32;

__device__ __forceinline__ unsigned short f2bf(float f) {
    unsigned u = __builtin_bit_cast(unsigned, f);
    unsigned r = (u + 0x7fffu + ((u >> 16) & 1u)) >> 16;
    return (unsigned short)r;
}
__device__ __forceinline__ float bf2f(unsigned short h) {
    return __builtin_bit_cast(float, (unsigned)h << 16);
}
__device__ __forceinline__ void split2(float v, unsigned short& h, unsigned short& l) {
    unsigned short hh = f2bf(v);
    h = hh;
    l = f2bf(v - bf2f(hh));
}
__device__ __forceinline__ void gld_lds16(const void* g, void* l) {
    __builtin_amdgcn_global_load_lds((const gu32*)g, (su32*)l, 16, 0, 0);
}

// wsplit: 16 blocks. W1|W2 (fp32 [k][n]) -> WhT/WlT (bf16 hi/lo, [n][k] transposed).
__global__ __launch_bounds__(256) void wsplit_kernel(
    const float* __restrict__ W1, const float* __restrict__ W2,
    unsigned short* __restrict__ WhT, unsigned short* __restrict__ WlT) {
    int w = blockIdx.x;
    int tid = threadIdx.x;
    int n = tid >> 1;               // 0..127
    int kb = (w << 5) + ((tid & 1) << 4);
    unsigned short hs[16], ls[16];
    #pragma unroll
    for (int kk = 0; kk < 16; kk++) {
        int k = kb + kk;
        float v = (n < 64) ? W1[k * PP + n] : W2[k * PP + (n - 64)];
        split2(v, hs[kk], ls[kk]);
    }
    uint4 a, bqq;
    a.x = hs[0] | ((unsigned)hs[1] << 16);   a.y = hs[2] | ((unsigned)hs[3] << 16);
    a.z = hs[4] | ((unsigned)hs[5] << 16);   a.w = hs[6] | ((unsigned)hs[7] << 16);
    bqq.x = hs[8] | ((unsigned)hs[9] << 16); bqq.y = hs[10] | ((unsigned)hs[11] << 16);
    bqq.z = hs[12] | ((unsigned)hs[13] << 16); bqq.w = hs[14] | ((unsigned)hs[15] << 16);
    *(uint4*)(WhT + (size_t)n * DD + kb) = a;
    *(uint4*)(WhT + (size_t)n * DD + kb + 8) = bqq;
    a.x = ls[0] | ((unsigned)ls[1] << 16);   a.y = ls[2] | ((unsigned)ls[3] << 16);
    a.z = ls[4] | ((unsigned)ls[5] << 16);   a.w = ls[6] | ((unsigned)ls[7] << 16);
    bqq.x = ls[8] | ((unsigned)ls[9] << 16); bqq.y = ls[10] | ((unsigned)ls[11] << 16);
    bqq.z = ls[12] | ((unsigned)ls[13] << 16); bqq.w = ls[14] | ((unsigned)ls[15] << 16);
    *(uint4*)(WlT + (size_t)n * DD + kb) = a;
    *(uint4*)(WlT + (size_t)n * DD + kb + 8) = bqq;
}

// prep: fused. blocks [0,512): x tiles -> xt (bf16 transpose);
//       [512,768): proj GEMM h = x @ [W1|W2], tile 16m x 128n, 3-term bf16-split MFMA,
//                  E1/E2 = exp2(CSCALE*(h+bias));
//       768: ec_proj -> E3.
// Shared-LDS union: transpose uses 16.6 KB, proj uses 41.5 KB.
__global__ __launch_bounds__(256, 3) void prep_kernel(
    const float* __restrict__ x, const float* __restrict__ ec,
    const unsigned short* __restrict__ WhT, const unsigned short* __restrict__ WlT,
    const float* __restrict__ b1, const float* __restrict__ b2,
    const float* __restrict__ W3, const float* __restrict__ b3,
    unsigned short* __restrict__ xt,
    float* __restrict__ E1, float* __restrict__ E2, float* __restrict__ E3) {
    __shared__ __align__(16) char smem[41472];
    int bid = blockIdx.x;
    int tid = threadIdx.x;
    if (bid < 512) {
        float (*tile)[65] = (float(*)[65])smem;
        int d0 = (bid & 7) << 6;
        int u0 = ((bid >> 3) & 15) << 6;
        int b = bid >> 7;
        int c4 = (tid & 15) << 2, r = tid >> 4;
        #pragma unroll
        for (int i = 0; i < 4; i++) {
            int row = r + (i << 4);
            float4 v = *(const float4*)(x + ((size_t)b * TT + u0 + row) * DD + d0 + c4);
            tile[row][c4 + 0] = v.x;
            tile[row][c4 + 1] = v.y;
            tile[row][c4 + 2] = v.z;
            tile[row][c4 + 3] = v.w;
        }
        __syncthreads();
        int dd = tid >> 2;
        int uq = (tid & 3) << 4;
        unsigned short us[16];
        #pragma unroll
        for (int j = 0; j < 16; j++) us[j] = f2bf(tile[uq + j][dd]);
        uint4 w0, w1;
        w0.x = us[0] | ((unsigned)us[1] << 16);  w0.y = us[2] | ((unsigned)us[3] << 16);
        w0.z = us[4] | ((unsigned)us[5] << 16);  w0.w = us[6] | ((unsigned)us[7] << 16);
        w1.x = us[8] | ((unsigned)us[9] << 16);  w1.y = us[10] | ((unsigned)us[11] << 16);
        w1.z = us[12] | ((unsigned)us[13] << 16); w1.w = us[14] | ((unsigned)us[15] << 16);
        unsigned short* dst = xt + ((size_t)b * DD + d0 + dd) * TT + u0 + uq;
        *(uint4*)dst = w0;
        *(uint4*)(dst + 8) = w1;
    } else if (bid < 768) {
        unsigned short (*AsH)[72] = (unsigned short(*)[72])(smem);
        unsigned short (*AsL)[72] = (unsigned short(*)[72])(smem + 2304);
        unsigned short (*BsH)[72] = (unsigned short(*)[72])(smem + 4608);
        unsigned short (*BsL)[72] = (unsigned short(*)[72])(smem + 23040);
        int m0 = (bid - 512) << 4;
        int lane = tid & 63;
        int wv = tid >> 6;
        int wn = wv << 5;
        int l15 = lane & 15;
        int quad = lane >> 4;

        v4f acc[2];
        acc[0] = (v4f){0.f, 0.f, 0.f, 0.f};
        acc[1] = acc[0];

        for (int k0 = 0; k0 < DD; k0 += 64) {
            __syncthreads();
            {
                int row = tid >> 4, k4 = (tid & 15) << 2;
                float4 v = *(const float4*)(x + (size_t)(m0 + row) * DD + k0 + k4);
                unsigned short h0, h1, h2, h3, l0, l1, l2, l3;
                split2(v.x, h0, l0); split2(v.y, h1, l1);
                split2(v.z, h2, l2); split2(v.w, h3, l3);
                uint2 hw, lw;
                hw.x = h0 | ((unsigned)h1 << 16); hw.y = h2 | ((unsigned)h3 << 16);
                lw.x = l0 | ((unsigned)l1 << 16); lw.y = l2 | ((unsigned)l3 << 16);
                *(uint2*)&AsH[row][k4] = hw;
                *(uint2*)&AsL[row][k4] = lw;
            }
            #pragma unroll
            for (int i = 0; i < 4; i++) {
                int s = (i << 8) + tid;
                int row = s >> 3, k8 = (s & 7) << 3;
                *(uint4*)&BsH[row][k8] = *(const uint4*)(WhT + (size_t)row * DD + k0 + k8);
                *(uint4*)&BsL[row][k8] = *(const uint4*)(WlT + (size_t)row * DD + k0 + k8);
            }
            __syncthreads();
            #pragma unroll
            for (int kk = 0; kk < 64; kk += 32) {
                int kc = kk + (quad << 3);
                v8s aH0 = *(const v8s*)&AsH[l15][kc];
                v8s aL0 = *(const v8s*)&AsL[l15][kc];
                #pragma unroll
                for (int nt = 0; nt < 2; nt++) {
                    v8s bH = *(const v8s*)&BsH[wn + (nt << 4) + l15][kc];
                    v8s bL = *(const v8s*)&BsL[wn + (nt << 4) + l15][kc];
                    acc[nt] = __builtin_amdgcn_mfma_f32_16x16x32_bf16(aH0, bH, acc[nt], 0, 0, 0);
                    acc[nt] = __builtin_amdgcn_mfma_f32_16x16x32_bf16(aH0, bL, acc[nt], 0, 0, 0);
                    acc[nt] = __builtin_amdgcn_mfma_f32_16x16x32_bf16(aL0, bH, acc[nt], 0, 0, 0);
                }
            }
        }
        #pragma unroll
        for (int nt = 0; nt < 2; nt++) {
            int n = wn + (nt << 4) + l15;     // 0..127
            int p = n & 63;
            float bias = (n < 64) ? b1[p] : b2[p];
            float* E = (n < 64) ? E1 : E2;
            int rbase = m0 + (quad << 2);
            #pragma unroll
            for (int r = 0; r < 4; r++) {
                float h = acc[nt][r] + bias;
                E[(size_t)(rbase + r) * PP + p] = __builtin_amdgcn_exp2f(h * CSCALE);
            }
        }
    } else {
        int b = tid >> 6, p = tid & 63;
        float a = b3[p];
        const float* e = ec + (size_t)b * MM;
        #pragma unroll 4
        for (int m = 0; m < MM; m++) a = fmaf(e[m], W3[m * PP + p], a);
        E3[b * PP + p] = __builtin_amdgcn_exp2f(a * CSCALE);
    }
}

// scores: block = (b, 4 t rows). lane: pp=tid&7 (8 p's), uu=tid>>3 (u slot).
// Scores kept in registers (own[32]); deferred softmax; bf16 at written directly.
// __launch_bounds__(256, 4): plain (256) made the allocator target 64 VGPR and
// SPILL own[32] to scratch (VGPR_Count=52 observed with a ~90-reg live set).
// The 128-VGPR budget keeps own[] resident.
__global__ __launch_bounds__(256, 4) void scores_kernel(
    const float* __restrict__ E1, const float* __restrict__ E2,
    const float* __restrict__ E3, const float* __restrict__ wa_w,
    const float* __restrict__ wa_b, unsigned short* __restrict__ at_bf) {
    __shared__ float sm[4][4];
    __shared__ float sl[4][4];
    int tid = threadIdx.x;
    int bid = blockIdx.x;
    int b = bid >> 8;
    int t0 = (bid & 255) << 2;
    int pp = tid & 7;
    int uu = tid >> 3;           // 0..31
    int p0 = pp << 3;
    int lane = tid & 63;
    int wv = tid >> 6;
    int my_i = pp & 3;
    bool pbit1 = (pp & 2) != 0;
    bool pbit0 = (pp & 1) != 0;

    float ww2[8], H[4][8];
    float base;
    {
        float4 wv0 = *(const float4*)(wa_w + p0);
        float4 wv1 = *(const float4*)(wa_w + p0 + 4);
        float s = wv0.x + wv0.y + wv0.z + wv0.w + wv1.x + wv1.y + wv1.z + wv1.w;
        s += __shfl_xor(s, 1, 64);
        s += __shfl_xor(s, 2, 64);
        s += __shfl_xor(s, 4, 64);
        base = (s + wa_b[0]) * L2E;
        ww2[0] = -2.f * L2E * wv0.x; ww2[1] = -2.f * L2E * wv0.y;
        ww2[2] = -2.f * L2E * wv0.z; ww2[3] = -2.f * L2E * wv0.w;
        ww2[4] = -2.f * L2E * wv1.x; ww2[5] = -2.f * L2E * wv1.y;
        ww2[6] = -2.f * L2E * wv1.z; ww2[7] = -2.f * L2E * wv1.w;
        float4 e3a = *(const float4*)(E3 + (b << 6) + p0);
        float4 e3b = *(const float4*)(E3 + (b << 6) + p0 + 4);
        #pragma unroll
        for (int i = 0; i < 4; i++) {
            const float* e1p = E1 + (((size_t)(b << 10) + t0 + i) << 6) + p0;
            float4 a = *(const float4*)e1p;
            float4 c = *(const float4*)(e1p + 4);
            H[i][0] = a.x * e3a.x; H[i][1] = a.y * e3a.y; H[i][2] = a.z * e3a.z; H[i][3] = a.w * e3a.w;
            H[i][4] = c.x * e3b.x; H[i][5] = c.y * e3b.y; H[i][6] = c.z * e3b.z; H[i][7] = c.w * e3b.w;
        }
    }

    float own[32];
    float mown = -1e30f;
    #pragma unroll
    for (int k = 0; k < 32; k++) {
        int u = (k << 5) + uu;
        const float* ep = E2 + (((size_t)(b << 10) + u) << 6) + p0;
        float4 e0 = *(const float4*)ep;
        float4 e1 = *(const float4*)(ep + 4);
        float ev[8] = {e0.x, e0.y, e0.z, e0.w, e1.x, e1.y, e1.z, e1.w};
        float s0 = 0.f, s1 = 0.f, s2 = 0.f, s3 = 0.f;
        #pragma unroll
        for (int j = 0; j < 8; j++) {
            s0 = fmaf(ww2[j], __builtin_amdgcn_rcpf(fmaf(H[0][j], ev[j], 1.0f)), s0);
            s1 = fmaf(ww2[j], __builtin_amdgcn_rcpf(fmaf(H[1][j], ev[j], 1.0f)), s1);
            s2 = fmaf(ww2[j], __builtin_amdgcn_rcpf(fmaf(H[2][j], ev[j], 1.0f)), s2);
            s3 = fmaf(ww2[j], __builtin_amdgcn_rcpf(fmaf(H[3][j], ev[j], 1.0f)), s3);
        }
        // 7-shfl butterfly: full-vec xor4, then select-based xor2/xor1
        s0 += __shfl_xor(s0, 4, 64);
        s1 += __shfl_xor(s1, 4, 64);
        s2 += __shfl_xor(s2, 4, 64);
        s3 += __shfl_xor(s3, 4, 64);
        float op0 = pbit1 ? s2 : s0;   // own pair (i bit1 == pp bit1)
        float op1 = pbit1 ? s3 : s1;
        float ot0 = pbit1 ? s0 : s2;   // other pair, send away
        float ot1 = pbit1 ? s1 : s3;
        op0 += __shfl_xor(ot0, 2, 64);
        op1 += __shfl_xor(ot1, 2, 64);
        float osel = pbit0 ? op1 : op0;
        float osnd = pbit0 ? op0 : op1;
        osel += __shfl_xor(osnd, 1, 64);
        float o = osel + base;
        own[k] = o;
        mown = fmaxf(mown, o);
    }
    // max across uu lanes (pp twins hold identical values)
    mown = fmaxf(mown, __shfl_xor(mown, 8, 64));
    mown = fmaxf(mown, __shfl_xor(mown, 16, 64));
    mown = fmaxf(mown, __shfl_xor(mown, 32, 64));
    if (lane < 4) sm[wv][lane] = mown;
    __syncthreads();
    float mx = fmaxf(fmaxf(sm[0][my_i], sm[1][my_i]), fmaxf(sm[2][my_i], sm[3][my_i]));

    float l = 0.f;
    #pragma unroll
    for (int k = 0; k < 32; k++) {
        float e = __builtin_amdgcn_exp2f(own[k] - mx);
        own[k] = e;
        l += e;
    }
    l += __shfl_xor(l, 8, 64);
    l += __shfl_xor(l, 16, 64);
    l += __shfl_xor(l, 32, 64);
    if (lane < 4) sl[wv][lane] = l;
    __syncthreads();
    float inv = 1.0f / (sl[0][my_i] + sl[1][my_i] + sl[2][my_i] + sl[3][my_i]);

    // pp twins (pp, pp+4) hold identical own[]; split the k-range between them.
    {
        size_t rowbase = ((size_t)((b << 10) + t0 + my_i)) << 10;
        int kbase = (pp >> 2) << 4;    // 0 or 16
        #pragma unroll
        for (int k = 0; k < 16; k++) {
            int kk = kbase + k;
            at_bf[rowbase + (kk << 5) + uu] = f2bf(own[kk] * inv);
        }
    }
}

// av: out[b] = at_bf[b] (1024x1024 bf16) @ Xt[b]^T via MFMA. 64x64 tile, BK=64.
// Staging via global_load_lds width=16; source-chunk XOR swizzle keeps unpadded
// LDS reads at free 2-way banking.
__global__ __launch_bounds__(256) void av_mfma_kernel(
    const unsigned short* __restrict__ at_bf, const unsigned short* __restrict__ xt,
    float* __restrict__ out) {
    __shared__ unsigned short As[64 * 64];  // 8 KB
    __shared__ unsigned short Bs[64 * 64];  // 8 KB
    int b = blockIdx.z;
    int m0 = blockIdx.y << 6;
    int n0 = blockIdx.x << 6;
    const unsigned short* A = at_bf + ((size_t)b << 20);
    const unsigned short* Bt = xt + (size_t)b * DD * TT;
    int tid = threadIdx.x;
    int lane = tid & 63;
    int wv = tid >> 6;
    int wm = (wv & 1) << 5;
    int wn = (wv >> 1) << 5;
    int l15 = lane & 15;
    int quad = lane >> 4;

    int sr = lane >> 3;           // 0..7 relative row within wave-instr
    int scg = (lane & 7) ^ sr;    // swizzled source chunk

    v4f acc00 = {0.f, 0.f, 0.f, 0.f}, acc01 = acc00, acc10 = acc00, acc11 = acc00;

    for (int k0 = 0; k0 < TT; k0 += 64) {
        __syncthreads();
        #pragma unroll
        for (int t = 0; t < 2; t++) {
            int r0 = (wv << 4) + (t << 3);    // wave-uniform row base, 8 rows/instr
            int row = r0 + sr;
            gld_lds16(A + (size_t)(m0 + row) * TT + k0 + (scg << 3), &As[r0 << 6]);
            gld_lds16(Bt + (size_t)(n0 + row) * TT + k0 + (scg << 3), &Bs[r0 << 6]);
        }
        __syncthreads();
        #pragma unroll
        for (int kq = 0; kq < 2; kq++) {
            int c = (kq << 2) + quad;
            int swz = (c ^ (l15 & 7)) << 3;
            v8s a0 = *(const v8s*)&As[((wm + l15) << 6) + swz];
            v8s a1 = *(const v8s*)&As[((wm + 16 + l15) << 6) + swz];
            v8s b0 = *(const v8s*)&Bs[((wn + l15) << 6) + swz];
            v8s b1 = *(const v8s*)&Bs[((wn + 16 + l15) << 6) + swz];
            acc00 = __builtin_amdgcn_mfma_f32_16x16x32_bf16(a0, b0, acc00, 0, 0, 0);
            acc01 = __builtin_amdgcn_mfma_f32_16x16x32_bf16(a0, b1, acc01, 0, 0, 0);
            acc10 = __builtin_amdgcn_mfma_f32_16x16x32_bf16(a1, b0, acc10, 0, 0, 0);
            acc11 = __builtin_amdgcn_mfma_f32_16x16x32_bf16(a1, b1, acc11, 0, 0, 0);
        }
    }
    float* C = out + (size_t)b * TT * DD;
    int rbase = m0 + wm + (quad << 2);
    int cn = n0 + wn + l15;
    #pragma unroll
    for (int r = 0; r < 4; r++) {
        C[(size_t)(rbase + r) * DD + cn]           = acc00[r];
        C[(size_t)(rbase + r) * DD + cn + 16]      = acc01[r];
        C[(size_t)(rbase + 16 + r) * DD + cn]      = acc10[r];
        C[(size_t)(rbase + 16 + r) * DD + cn + 16] = acc11[r];
    }
}

extern "C" void kernel_launch(void* const* d_in, const int* in_sizes, int n_in,
                              void* d_out, int out_size, void* d_ws, size_t ws_size,
                              hipStream_t stream) {
    const float* inputs = (const float*)d_in[0];
    const float* ec     = (const float*)d_in[1];
    const float* W1     = (const float*)d_in[2];
    const float* b1     = (const float*)d_in[3];
    const float* W2     = (const float*)d_in[4];
    const float* b2     = (const float*)d_in[5];
    const float* W3     = (const float*)d_in[6];
    const float* b3     = (const float*)d_in[7];
    const float* wa_w   = (const float*)d_in[8];
    const float* wa_b   = (const float*)d_in[9];
    float* out = (float*)d_out;

    // ws layout (float units) — R5/R7/R8-proven 14,682,112-byte footprint:
    //   E1[262144] | E2[262144] | E3[512] | at_bf (2097152 f) | xt (1048576 f)
    // WhT/WlT alias the front of at_bf (live range wsplit->prep only).
    float* ws = (float*)d_ws;
    float* E1 = ws;
    float* E2 = ws + 262144;
    float* E3 = ws + 524288;
    unsigned short* at_bf = (unsigned short*)(ws + 524800);
    unsigned short* xt    = (unsigned short*)(ws + 524800 + 2097152);
    unsigned short* WhT   = at_bf;            // 65536 shorts
    unsigned short* WlT   = at_bf + 65536;    // 65536 shorts

    hipLaunchKernelGGL(wsplit_kernel, dim3(16), dim3(256), 0, stream,
                       W1, W2, WhT, WlT);
    hipLaunchKernelGGL(prep_kernel, dim3(769), dim3(256), 0, stream,
                       inputs, ec, WhT, WlT, b1, b2, W3, b3, xt, E1, E2, E3);
    hipLaunchKernelGGL(scores_kernel, dim3(1024), dim3(256), 0, stream,
                       E1, E2, E3, wa_w, wa_b, at_bf);
    hipLaunchKernelGGL(av_mfma_kernel, dim3(DD / 64, TT / 64, BB), dim3(256), 0, stream,
                       at_bf, xt, out);
}